// Round 1
// baseline (236.657 us; speedup 1.0000x reference)
//
#include <hip/hip_runtime.h>
#include <math.h>

#define REGION_MAX 116
#define EMB 768
#define DIM_D 182
#define DIM_H 218
#define DIM_W 182

// --- setup: M = inv(aal_affine) @ mri_affine, store top 3 rows (12 floats) ---
__global__ void compute_M_kernel(const float* __restrict__ mri,
                                 const float* __restrict__ aal,
                                 float* __restrict__ M) {
    if (threadIdx.x != 0 || blockIdx.x != 0) return;
    float a[4][8];
    for (int i = 0; i < 4; ++i)
        for (int j = 0; j < 4; ++j) {
            a[i][j]     = aal[i * 4 + j];
            a[i][j + 4] = (i == j) ? 1.0f : 0.0f;
        }
    // Gauss-Jordan with partial pivoting
    for (int c = 0; c < 4; ++c) {
        int piv = c;
        float best = fabsf(a[c][c]);
        for (int r = c + 1; r < 4; ++r) {
            float v = fabsf(a[r][c]);
            if (v > best) { best = v; piv = r; }
        }
        if (piv != c)
            for (int j = 0; j < 8; ++j) {
                float t = a[c][j]; a[c][j] = a[piv][j]; a[piv][j] = t;
            }
        float inv = 1.0f / a[c][c];
        for (int j = 0; j < 8; ++j) a[c][j] *= inv;
        for (int r = 0; r < 4; ++r) {
            if (r == c) continue;
            float f = a[r][c];
            for (int j = 0; j < 8; ++j) a[r][j] -= f * a[c][j];
        }
    }
    // M = inv(aal) @ mri  (rows 0..2 only; affine last row unused)
    for (int i = 0; i < 3; ++i)
        for (int j = 0; j < 4; ++j) {
            float s = 0.0f;
            for (int k = 0; k < 4; ++k) s += a[i][4 + k] * mri[k * 4 + j];
            M[i * 4 + j] = s;
        }
}

// --- main: one wave (64 lanes) per point; copy 768-float row as 192 float4 ---
__global__ __launch_bounds__(256) void aal_embed_kernel(
    const float* __restrict__ centers,   // [P,3]
    const float* __restrict__ M,         // 12 floats
    const float* __restrict__ vol,       // [D,H,W]
    const float* __restrict__ table,     // [117, EMB]
    float* __restrict__ out,             // [P, EMB]
    int P) {
    int wave = (blockIdx.x * blockDim.x + threadIdx.x) >> 6;
    int lane = threadIdx.x & 63;
    if (wave >= P) return;

    // wave-uniform: every lane computes the same point (no divergence, cheap)
    float px = centers[wave * 3 + 0];
    float py = centers[wave * 3 + 1];
    float pz = centers[wave * 3 + 2];

    float fx = M[0] * px + M[1] * py + M[2]  * pz + M[3];
    float fy = M[4] * px + M[5] * py + M[6]  * pz + M[7];
    float fz = M[8] * px + M[9] * py + M[10] * pz + M[11];

    int x = (int)rintf(fx);   // round half-to-even, matches jnp.round
    int y = (int)rintf(fy);
    int z = (int)rintf(fz);

    bool inb = (x >= 0) & (x < DIM_D) & (y >= 0) & (y < DIM_H) &
               (z >= 0) & (z < DIM_W);
    int cx = min(max(x, 0), DIM_D - 1);
    int cy = min(max(y, 0), DIM_H - 1);
    int cz = min(max(z, 0), DIM_W - 1);

    int region = (int)vol[((size_t)cx * DIM_H + cy) * DIM_W + cz];  // trunc, matches astype(int32)
    int rid = (inb && region >= 0 && region <= REGION_MAX) ? region : 0;

    const float4* __restrict__ src = (const float4*)(table + (size_t)rid * EMB);
    float4* __restrict__ dst = (float4*)(out + (size_t)wave * EMB);
    // EMB/4 = 192 float4 per row; 64 lanes -> 3 each, fully coalesced
    dst[lane]       = src[lane];
    dst[lane + 64]  = src[lane + 64];
    dst[lane + 128] = src[lane + 128];
}

extern "C" void kernel_launch(void* const* d_in, const int* in_sizes, int n_in,
                              void* d_out, int out_size, void* d_ws, size_t ws_size,
                              hipStream_t stream) {
    const float* centers = (const float*)d_in[0];   // [B,N,3] f32
    const float* mri     = (const float*)d_in[1];   // [4,4]
    const float* aal     = (const float*)d_in[2];   // [4,4]
    const float* vol     = (const float*)d_in[3];   // [D,H,W]
    const float* table   = (const float*)d_in[4];   // [117,768]
    float* out = (float*)d_out;
    float* M   = (float*)d_ws;                      // 12 floats

    int P = in_sizes[0] / 3;                        // 65536

    compute_M_kernel<<<1, 64, 0, stream>>>(mri, aal, M);

    int waves_per_block = 256 / 64;
    int blocks = (P + waves_per_block - 1) / waves_per_block;
    aal_embed_kernel<<<blocks, 256, 0, stream>>>(centers, M, vol, table, out, P);
}